// Round 1
// baseline (34398.431 us; speedup 1.0000x reference)
//
#include <hip/hip_runtime.h>
#include <math.h>

// MetaGCRN: B=64 T=12 N=1024 D=1 H=64 E=10 K=3 HOR=12 YC=1 OUT=1
// Layouts in workspace (all fp32):
//   h   : [n][b][hh]      == (N, B*H) row-major   (row = n*64+b when viewed (NB,H))
//   X   : [n][b][c]       == (N, B*C) row-major   (also (NB,C) row-major)
//   Y1,Y2 same as X;  r,z : (NB,H);  S matrices: (N,N)
// Sequence per GRU step:
//   build X=[x|h] -> Y1=S@X,Y2=S2@X -> gate GEMM -> z,r -> X.state=z*h ->
//   Y1,Y2 again -> update GEMM -> h = r*h+(1-r)*tanh(...)

namespace {
constexpr int Bc = 64, Tc = 12, Nc = 1024, Hc = 64, Ec = 10;
constexpr int NBc = Nc * Bc;   // 65536
constexpr int CE = 65;         // D + H
constexpr int CD = 66;         // OUT + YC + H
}

// ---------- scores = in @ in^T (Kd inner), relu, row softmax ----------
__global__ __launch_bounds__(256) void k_scores(const float* __restrict__ in, int Kd,
                                                float* __restrict__ S) {
  __shared__ float rowbuf[640];
  __shared__ float sred[8];
  int n = blockIdx.x;
  for (int j = threadIdx.x; j < Kd; j += 256) rowbuf[j] = in[(size_t)n * Kd + j];
  __syncthreads();
  float v[4];
#pragma unroll
  for (int i = 0; i < 4; i++) {
    int m = threadIdx.x + i * 256;
    const float* rm = in + (size_t)m * Kd;
    float acc = 0.f;
    for (int j = 0; j < Kd; j++) acc = fmaf(rowbuf[j], rm[j], acc);
    v[i] = fmaxf(acc, 0.f);
  }
  float mx = fmaxf(fmaxf(v[0], v[1]), fmaxf(v[2], v[3]));
  for (int off = 32; off > 0; off >>= 1) mx = fmaxf(mx, __shfl_down(mx, off));
  if ((threadIdx.x & 63) == 0) sred[threadIdx.x >> 6] = mx;
  __syncthreads();
  float rmax = fmaxf(fmaxf(sred[0], sred[1]), fmaxf(sred[2], sred[3]));
  float s = 0.f;
#pragma unroll
  for (int i = 0; i < 4; i++) { v[i] = expf(v[i] - rmax); s += v[i]; }
  for (int off = 32; off > 0; off >>= 1) s += __shfl_down(s, off);
  if ((threadIdx.x & 63) == 0) sred[4 + (threadIdx.x >> 6)] = s;
  __syncthreads();
  float inv = 1.f / (sred[4] + sred[5] + sred[6] + sred[7]);
#pragma unroll
  for (int i = 0; i < 4; i++) S[(size_t)n * Nc + threadIdx.x + i * 256] = v[i] * inv;
}

// ---------- S2 = 2*S@S - I ----------
__global__ __launch_bounds__(256) void k_s2(const float* __restrict__ S,
                                            float* __restrict__ S2) {
  __shared__ float At[16][64];
  __shared__ float Bt[16][64];
  int i0 = blockIdx.y * 64, j0 = blockIdx.x * 64;
  int tx = threadIdx.x & 15, ty = threadIdx.x >> 4;
  float acc[4][4] = {};
  for (int k0 = 0; k0 < Nc; k0 += 16) {
    for (int u = threadIdx.x; u < 1024; u += 256) {
      int i = u >> 4, k = u & 15;
      At[k][i] = S[(size_t)(i0 + i) * Nc + k0 + k];
    }
    for (int u = threadIdx.x; u < 1024; u += 256) {
      int k = u >> 6, j = u & 63;
      Bt[k][j] = S[(size_t)(k0 + k) * Nc + j0 + j];
    }
    __syncthreads();
#pragma unroll
    for (int kk = 0; kk < 16; kk++) {
      float a[4], b[4];
#pragma unroll
      for (int p = 0; p < 4; p++) a[p] = At[kk][ty * 4 + p];
#pragma unroll
      for (int q = 0; q < 4; q++) b[q] = Bt[kk][tx * 4 + q];
#pragma unroll
      for (int p = 0; p < 4; p++)
#pragma unroll
        for (int q = 0; q < 4; q++) acc[p][q] = fmaf(a[p], b[q], acc[p][q]);
    }
    __syncthreads();
  }
  for (int p = 0; p < 4; p++)
    for (int q = 0; q < 4; q++) {
      int i = i0 + ty * 4 + p, j = j0 + tx * 4 + q;
      S2[(size_t)i * Nc + j] = 2.f * acc[p][q] - (i == j ? 1.f : 0.f);
    }
}

// ---------- Y1 = S1 @ X, Y2 = S2 @ X  (X: (N, ncols)) ----------
__global__ __launch_bounds__(256) void k_ygemm_dual(const float* __restrict__ S1,
                                                    const float* __restrict__ S2,
                                                    const float* __restrict__ X,
                                                    float* __restrict__ Y1,
                                                    float* __restrict__ Y2, int ncols) {
  __shared__ float A1[16][64];
  __shared__ float A2[16][64];
  __shared__ float Bt[16][64];
  int i0 = blockIdx.y * 64, j0 = blockIdx.x * 64;
  int tx = threadIdx.x & 15, ty = threadIdx.x >> 4;
  float acc1[4][4] = {}, acc2[4][4] = {};
  for (int k0 = 0; k0 < Nc; k0 += 16) {
    for (int u = threadIdx.x; u < 1024; u += 256) {
      int i = u >> 4, k = u & 15;
      size_t a = (size_t)(i0 + i) * Nc + k0 + k;
      A1[k][i] = S1[a];
      A2[k][i] = S2[a];
    }
    for (int u = threadIdx.x; u < 1024; u += 256) {
      int k = u >> 6, j = u & 63;
      Bt[k][j] = X[(size_t)(k0 + k) * ncols + j0 + j];
    }
    __syncthreads();
#pragma unroll
    for (int kk = 0; kk < 16; kk++) {
      float a1[4], a2[4], b[4];
#pragma unroll
      for (int p = 0; p < 4; p++) { a1[p] = A1[kk][ty * 4 + p]; a2[p] = A2[kk][ty * 4 + p]; }
#pragma unroll
      for (int q = 0; q < 4; q++) b[q] = Bt[kk][tx * 4 + q];
#pragma unroll
      for (int p = 0; p < 4; p++)
#pragma unroll
        for (int q = 0; q < 4; q++) {
          acc1[p][q] = fmaf(a1[p], b[q], acc1[p][q]);
          acc2[p][q] = fmaf(a2[p], b[q], acc2[p][q]);
        }
    }
    __syncthreads();
  }
  for (int p = 0; p < 4; p++)
    for (int q = 0; q < 4; q++) {
      size_t a = (size_t)(i0 + ty * 4 + p) * ncols + j0 + tx * 4 + q;
      Y1[a] = acc1[p][q];
      Y2[a] = acc2[p][q];
    }
}

// ---------- gate GEMM: pre = [X|Y1|Y2] @ W(3C x 128) + b; z,r = sigmoid ----------
__global__ __launch_bounds__(256) void k_gate(const float* __restrict__ X,
                                              const float* __restrict__ Y1,
                                              const float* __restrict__ Y2,
                                              const float* __restrict__ W,
                                              const float* __restrict__ bias,
                                              float* __restrict__ zbuf,
                                              float* __restrict__ rbuf, int C) {
  __shared__ float At[16][64];
  __shared__ float Bt[16][64];
  int row0 = blockIdx.y * 64;
  int j0 = blockIdx.x * 64;  // 0 -> z half, 64 -> r half
  int K3 = 3 * C;
  int tx = threadIdx.x & 15, ty = threadIdx.x >> 4;
  float acc[4][4] = {};
  for (int k0 = 0; k0 < K3; k0 += 16) {
    for (int u = threadIdx.x; u < 1024; u += 256) {
      int rr = u >> 4, k = u & 15;
      int c = k0 + k;
      float v = 0.f;
      if (c < K3) {
        const float* base;
        int cc;
        if (c < C) { base = X; cc = c; }
        else if (c < 2 * C) { base = Y1; cc = c - C; }
        else { base = Y2; cc = c - 2 * C; }
        v = base[(size_t)(row0 + rr) * C + cc];
      }
      At[k][rr] = v;
    }
    for (int u = threadIdx.x; u < 1024; u += 256) {
      int k = u >> 6, j = u & 63;
      int c = k0 + k;
      Bt[k][j] = (c < K3) ? W[(size_t)c * 128 + j0 + j] : 0.f;
    }
    __syncthreads();
#pragma unroll
    for (int kk = 0; kk < 16; kk++) {
      float a[4], b[4];
#pragma unroll
      for (int p = 0; p < 4; p++) a[p] = At[kk][ty * 4 + p];
#pragma unroll
      for (int q = 0; q < 4; q++) b[q] = Bt[kk][tx * 4 + q];
#pragma unroll
      for (int p = 0; p < 4; p++)
#pragma unroll
        for (int q = 0; q < 4; q++) acc[p][q] = fmaf(a[p], b[q], acc[p][q]);
    }
    __syncthreads();
  }
  for (int p = 0; p < 4; p++)
    for (int q = 0; q < 4; q++) {
      int row = row0 + ty * 4 + p;
      int col = j0 + tx * 4 + q;
      float sg = 1.f / (1.f + expf(-(acc[p][q] + bias[col])));
      if (col < 64) zbuf[(size_t)row * 64 + col] = sg;
      else rbuf[(size_t)row * 64 + col - 64] = sg;
    }
}

// ---------- X.state = z * h ----------
__global__ __launch_bounds__(256) void k_apply_z(float* __restrict__ X,
                                                 const float* __restrict__ zbuf,
                                                 const float* __restrict__ h, int C,
                                                 int off) {
  int idx = blockIdx.x * 256 + threadIdx.x;
  if (idx >= NBc * Hc) return;
  int row = idx >> 6, i = idx & 63;
  X[(size_t)row * C + off + i] = zbuf[idx] * h[idx];
}

// ---------- update GEMM: hc = tanh([X|Y1|Y2]@Wu + bu); h = r*h + (1-r)*hc ----------
__global__ __launch_bounds__(256) void k_update(const float* __restrict__ X,
                                                const float* __restrict__ Y1,
                                                const float* __restrict__ Y2,
                                                const float* __restrict__ W,
                                                const float* __restrict__ bias,
                                                const float* __restrict__ rbuf,
                                                float* __restrict__ h, int C) {
  __shared__ float At[16][64];
  __shared__ float Bt[16][64];
  int row0 = blockIdx.y * 64;
  int K3 = 3 * C;
  int tx = threadIdx.x & 15, ty = threadIdx.x >> 4;
  float acc[4][4] = {};
  for (int k0 = 0; k0 < K3; k0 += 16) {
    for (int u = threadIdx.x; u < 1024; u += 256) {
      int rr = u >> 4, k = u & 15;
      int c = k0 + k;
      float v = 0.f;
      if (c < K3) {
        const float* base;
        int cc;
        if (c < C) { base = X; cc = c; }
        else if (c < 2 * C) { base = Y1; cc = c - C; }
        else { base = Y2; cc = c - 2 * C; }
        v = base[(size_t)(row0 + rr) * C + cc];
      }
      At[k][rr] = v;
    }
    for (int u = threadIdx.x; u < 1024; u += 256) {
      int k = u >> 6, j = u & 63;
      int c = k0 + k;
      Bt[k][j] = (c < K3) ? W[(size_t)c * 64 + j] : 0.f;
    }
    __syncthreads();
#pragma unroll
    for (int kk = 0; kk < 16; kk++) {
      float a[4], b[4];
#pragma unroll
      for (int p = 0; p < 4; p++) a[p] = At[kk][ty * 4 + p];
#pragma unroll
      for (int q = 0; q < 4; q++) b[q] = Bt[kk][tx * 4 + q];
#pragma unroll
      for (int p = 0; p < 4; p++)
#pragma unroll
        for (int q = 0; q < 4; q++) acc[p][q] = fmaf(a[p], b[q], acc[p][q]);
    }
    __syncthreads();
  }
  for (int p = 0; p < 4; p++)
    for (int q = 0; q < 4; q++) {
      int row = row0 + ty * 4 + p;
      int col = tx * 4 + q;
      float hc = tanhf(acc[p][q] + bias[col]);
      size_t idx = (size_t)row * 64 + col;
      float rr = rbuf[idx];
      h[idx] = rr * h[idx] + (1.f - rr) * hc;
    }
}

// ---------- build X = [x_t | h]  (enc) ----------
__global__ __launch_bounds__(256) void k_bx_enc(const float* __restrict__ x,
                                                const float* __restrict__ h,
                                                float* __restrict__ X, int t) {
  int idx = blockIdx.x * 256 + threadIdx.x;
  if (idx >= NBc * CE) return;
  int row = idx / CE, c = idx % CE;
  float v;
  if (c == 0) {
    int n = row >> 6, b = row & 63;
    v = x[(size_t)b * (Tc * Nc) + (size_t)t * Nc + n];
  } else {
    v = h[(size_t)row * Hc + (c - 1)];
  }
  X[idx] = v;
}

// ---------- build X = [go | ycov_t | h]  (dec) ----------
__global__ __launch_bounds__(256) void k_bx_dec(const float* __restrict__ go,
                                                const float* __restrict__ ycov,
                                                const float* __restrict__ h,
                                                float* __restrict__ X, int t) {
  int idx = blockIdx.x * 256 + threadIdx.x;
  if (idx >= NBc * CD) return;
  int row = idx / CD, c = idx % CD;
  float v;
  if (c == 0) {
    v = go[row];
  } else if (c == 1) {
    int n = row >> 6, b = row & 63;
    v = ycov[(size_t)b * (Tc * Nc) + (size_t)t * Nc + n];
  } else {
    v = h[(size_t)row * Hc + (c - 2)];
  }
  X[idx] = v;
}

// ---------- de[n][b*10+e] = sum_hh h[n][b][hh] * FC[hh][e] ----------
__global__ __launch_bounds__(256) void k_de(const float* __restrict__ h,
                                            const float* __restrict__ fc,
                                            float* __restrict__ de) {
  __shared__ float fcs[Hc * Ec];
  for (int j = threadIdx.x; j < Hc * Ec; j += 256) fcs[j] = fc[j];
  __syncthreads();
  int idx = blockIdx.x * 256 + threadIdx.x;
  if (idx >= Nc * Bc * Ec) return;
  int n = idx / (Bc * Ec);
  int rem = idx % (Bc * Ec);
  int b = rem / Ec, e = rem % Ec;
  const float* hp = h + (size_t)n * (Bc * Hc) + (size_t)b * Hc;
  float acc = 0.f;
#pragma unroll 8
  for (int hh = 0; hh < Hc; hh++) acc = fmaf(hp[hh], fcs[hh * Ec + e], acc);
  de[idx] = acc;
}

// ---------- go init: go[n][b] = x[b][T-1][n][0] ----------
__global__ __launch_bounds__(256) void k_go_init(const float* __restrict__ x,
                                                 float* __restrict__ go) {
  int idx = blockIdx.x * 256 + threadIdx.x;
  if (idx >= NBc) return;
  int n = idx >> 6, b = idx & 63;
  go[idx] = x[(size_t)b * (Tc * Nc) + (size_t)(Tc - 1) * Nc + n];
}

// ---------- proj: go = h @ pw + pb ; out[b][t][n] = go ----------
__global__ __launch_bounds__(256) void k_proj(const float* __restrict__ h,
                                              const float* __restrict__ pw,
                                              const float* __restrict__ pb,
                                              float* __restrict__ go,
                                              float* __restrict__ out, int t) {
  int idx = blockIdx.x * 256 + threadIdx.x;
  if (idx >= NBc) return;
  int n = idx >> 6, b = idx & 63;
  const float* hp = h + (size_t)idx * Hc;
  float acc = pb[0];
#pragma unroll 8
  for (int i = 0; i < Hc; i++) acc = fmaf(hp[i], pw[i], acc);
  go[idx] = acc;
  out[(size_t)b * (Tc * Nc) + (size_t)t * Nc + n] = acc;
}

extern "C" void kernel_launch(void* const* d_in, const int* in_sizes, int n_in,
                              void* d_out, int out_size, void* d_ws, size_t ws_size,
                              hipStream_t stream) {
  (void)in_sizes; (void)n_in; (void)out_size; (void)ws_size;
  const float* x    = (const float*)d_in[0];
  const float* ycov = (const float*)d_in[1];
  const float* emb  = (const float*)d_in[2];
  const float* fce  = (const float*)d_in[3];
  const float* egw  = (const float*)d_in[4];
  const float* egb  = (const float*)d_in[5];
  const float* euw  = (const float*)d_in[6];
  const float* eub  = (const float*)d_in[7];
  const float* dgw  = (const float*)d_in[8];
  const float* dgb  = (const float*)d_in[9];
  const float* duw  = (const float*)d_in[10];
  const float* dub  = (const float*)d_in[11];
  const float* pw   = (const float*)d_in[12];
  const float* pb   = (const float*)d_in[13];
  float* out = (float*)d_out;

  float* w = (float*)d_ws;
  size_t o = 0;
  float* S1e = w + o; o += (size_t)Nc * Nc;
  float* S2e = w + o; o += (size_t)Nc * Nc;
  float* S1d = w + o; o += (size_t)Nc * Nc;
  float* S2d = w + o; o += (size_t)Nc * Nc;
  float* Hst = w + o; o += (size_t)NBc * Hc;
  float* Xb  = w + o; o += (size_t)NBc * CD;
  float* Y1  = w + o; o += (size_t)NBc * CD;
  float* Y2  = w + o; o += (size_t)NBc * CD;
  float* Rb  = w + o; o += (size_t)NBc * Hc;
  float* Zb  = w + o; o += (size_t)NBc * Hc;
  float* DE  = w + o; o += (size_t)Nc * Bc * Ec;
  float* GO  = w + o; o += (size_t)NBc;

  hipMemsetAsync(Hst, 0, (size_t)NBc * Hc * sizeof(float), stream);

  // encoder supports
  k_scores<<<Nc, 256, 0, stream>>>(emb, Ec, S1e);
  k_s2<<<dim3(16, 16), 256, 0, stream>>>(S1e, S2e);

  const int ncolsE = Bc * CE;  // 4160
  const int ncolsD = Bc * CD;  // 4224
  const int gBXe = (NBc * CE + 255) / 256;
  const int gBXd = (NBc * CD + 255) / 256;
  const int gAZ = (NBc * Hc) / 256;

  for (int t = 0; t < Tc; t++) {
    k_bx_enc<<<gBXe, 256, 0, stream>>>(x, Hst, Xb, t);
    k_ygemm_dual<<<dim3(ncolsE / 64, 16), 256, 0, stream>>>(S1e, S2e, Xb, Y1, Y2, ncolsE);
    k_gate<<<dim3(2, 1024), 256, 0, stream>>>(Xb, Y1, Y2, egw, egb, Zb, Rb, CE);
    k_apply_z<<<gAZ, 256, 0, stream>>>(Xb, Zb, Hst, CE, 1);
    k_ygemm_dual<<<dim3(ncolsE / 64, 16), 256, 0, stream>>>(S1e, S2e, Xb, Y1, Y2, ncolsE);
    k_update<<<dim3(1, 1024), 256, 0, stream>>>(Xb, Y1, Y2, euw, eub, Rb, Hst, CE);
  }

  // decoder supports from dec_emb = h_T @ FC_E, scores summed over batch
  k_de<<<(Nc * Bc * Ec + 255) / 256, 256, 0, stream>>>(Hst, fce, DE);
  k_scores<<<Nc, 256, 0, stream>>>(DE, Bc * Ec, S1d);
  k_s2<<<dim3(16, 16), 256, 0, stream>>>(S1d, S2d);
  k_go_init<<<NBc / 256, 256, 0, stream>>>(x, GO);

  for (int t = 0; t < Tc; t++) {
    k_bx_dec<<<gBXd, 256, 0, stream>>>(GO, ycov, Hst, Xb, t);
    k_ygemm_dual<<<dim3(ncolsD / 64, 16), 256, 0, stream>>>(S1d, S2d, Xb, Y1, Y2, ncolsD);
    k_gate<<<dim3(2, 1024), 256, 0, stream>>>(Xb, Y1, Y2, dgw, dgb, Zb, Rb, CD);
    k_apply_z<<<gAZ, 256, 0, stream>>>(Xb, Zb, Hst, CD, 2);
    k_ygemm_dual<<<dim3(ncolsD / 64, 16), 256, 0, stream>>>(S1d, S2d, Xb, Y1, Y2, ncolsD);
    k_update<<<dim3(1, 1024), 256, 0, stream>>>(Xb, Y1, Y2, duw, dub, Rb, Hst, CD);
    k_proj<<<NBc / 256, 256, 0, stream>>>(Hst, pw, pb, GO, out, t);
  }
}

// Round 2
// 7443.317 us; speedup vs baseline: 4.6214x; 4.6214x over previous
//
#include <hip/hip_runtime.h>
#include <math.h>

typedef __attribute__((ext_vector_type(8))) short bf16x8;
typedef __attribute__((ext_vector_type(4))) float f32x4;
typedef unsigned short u16;

namespace {
constexpr int Bc = 64, Tc = 12, Nn = 1024, Hc = 64, Ec = 10;
constexpr int NB = Nn * Bc;  // 65536
constexpr int Cc = 66;       // unified channel count (enc uses 65, col 65 zeroed)
constexpr int SA = 208;      // XA row stride in elements ([X(66)|Y1(66)|Y2(66)|pad10])
constexpr int KP = 224;      // padded K for gate/update GEMMs (7 x 32)
constexpr int TN = Tc * Nn;  // 12288
}

// async global->LDS 16B (wave-uniform LDS base + lane*16)
__device__ __forceinline__ void gld16(const void* g, void* l) {
  __builtin_amdgcn_global_load_lds(
      (const __attribute__((address_space(1))) void*)g,
      (__attribute__((address_space(3))) void*)l, 16, 0, 0);
}

// split fp32 -> bf16 hi + bf16 lo (RNE both); hi+lo reproduces v to ~2^-16 rel
__device__ __forceinline__ void split_bf(float v, u16& h, u16& l) {
  unsigned u = __float_as_uint(v);
  unsigned hu = (u + 0x7FFFu + ((u >> 16) & 1u)) & 0xFFFF0000u;
  h = (u16)(hu >> 16);
  float r = v - __uint_as_float(hu);
  unsigned u2 = __float_as_uint(r);
  l = (u16)((u2 + 0x7FFFu + ((u2 >> 16) & 1u)) >> 16);
}

// ---------- scores = relu(in @ in^T) row-softmax ----------
__global__ __launch_bounds__(256) void k_scores(const float* __restrict__ in, int Kd,
                                                float* __restrict__ S) {
  __shared__ float rowbuf[640];
  __shared__ float sred[8];
  int n = blockIdx.x;
  for (int j = threadIdx.x; j < Kd; j += 256) rowbuf[j] = in[(size_t)n * Kd + j];
  __syncthreads();
  float v[4];
#pragma unroll
  for (int i = 0; i < 4; i++) {
    int m = threadIdx.x + i * 256;
    const float* rm = in + (size_t)m * Kd;
    float acc = 0.f;
    for (int j = 0; j < Kd; j++) acc = fmaf(rowbuf[j], rm[j], acc);
    v[i] = fmaxf(acc, 0.f);
  }
  float mx = fmaxf(fmaxf(v[0], v[1]), fmaxf(v[2], v[3]));
  for (int off = 32; off > 0; off >>= 1) mx = fmaxf(mx, __shfl_down(mx, off));
  if ((threadIdx.x & 63) == 0) sred[threadIdx.x >> 6] = mx;
  __syncthreads();
  float rmax = fmaxf(fmaxf(sred[0], sred[1]), fmaxf(sred[2], sred[3]));
  float s = 0.f;
#pragma unroll
  for (int i = 0; i < 4; i++) { v[i] = expf(v[i] - rmax); s += v[i]; }
  for (int off = 32; off > 0; off >>= 1) s += __shfl_down(s, off);
  if ((threadIdx.x & 63) == 0) sred[4 + (threadIdx.x >> 6)] = s;
  __syncthreads();
  float inv = 1.f / (sred[4] + sred[5] + sred[6] + sred[7]);
#pragma unroll
  for (int i = 0; i < 4; i++) S[(size_t)n * Nn + threadIdx.x + i * 256] = v[i] * inv;
}

// ---------- S2 = 2*S@S - I (fp32, 2 dispatches total, non-critical) ----------
__global__ __launch_bounds__(256) void k_s2(const float* __restrict__ S,
                                            float* __restrict__ S2) {
  __shared__ float At[16][64];
  __shared__ float Bt[16][64];
  int i0 = blockIdx.y * 64, j0 = blockIdx.x * 64;
  int tx = threadIdx.x & 15, ty = threadIdx.x >> 4;
  float acc[4][4] = {};
  for (int k0 = 0; k0 < Nn; k0 += 16) {
    for (int u = threadIdx.x; u < 1024; u += 256) {
      int i = u >> 4, k = u & 15;
      At[k][i] = S[(size_t)(i0 + i) * Nn + k0 + k];
    }
    for (int u = threadIdx.x; u < 1024; u += 256) {
      int k = u >> 6, j = u & 63;
      Bt[k][j] = S[(size_t)(k0 + k) * Nn + j0 + j];
    }
    __syncthreads();
#pragma unroll
    for (int kk = 0; kk < 16; kk++) {
      float a[4], b[4];
#pragma unroll
      for (int p = 0; p < 4; p++) a[p] = At[kk][ty * 4 + p];
#pragma unroll
      for (int q = 0; q < 4; q++) b[q] = Bt[kk][tx * 4 + q];
#pragma unroll
      for (int p = 0; p < 4; p++)
#pragma unroll
        for (int q = 0; q < 4; q++) acc[p][q] = fmaf(a[p], b[q], acc[p][q]);
    }
    __syncthreads();
  }
  for (int p = 0; p < 4; p++)
    for (int q = 0; q < 4; q++) {
      int i = i0 + ty * 4 + p, j = j0 + tx * 4 + q;
      S2[(size_t)i * Nn + j] = 2.f * acc[p][q] - (i == j ? 1.f : 0.f);
    }
}

// ---------- split S1,S2 fp32 -> bf16 hi/lo ----------
__global__ __launch_bounds__(256) void k_split2(const float* __restrict__ A,
                                                const float* __restrict__ B,
                                                u16* __restrict__ Ah, u16* __restrict__ Al,
                                                u16* __restrict__ Bh, u16* __restrict__ Bl) {
  int i = blockIdx.x * 256 + threadIdx.x;
  if (i >= Nn * Nn) return;
  u16 h, l;
  split_bf(A[i], h, l); Ah[i] = h; Al[i] = l;
  split_bf(B[i], h, l); Bh[i] = h; Bl[i] = l;
}

// ---------- Wt prep: Wt[n][kpad] hi/lo, kpad = chunk*66 + c; zeros for pad ----------
__global__ __launch_bounds__(256) void k_prep_wt(const float* __restrict__ W, int Csrc,
                                                 int ncol, u16* __restrict__ Wh,
                                                 u16* __restrict__ Wl) {
  int idx = blockIdx.x * 256 + threadIdx.x;
  if (idx >= ncol * KP) return;
  int n = idx / KP, kp = idx % KP;
  int chunk = kp / Cc, c = kp % Cc;
  float v = 0.f;
  if (kp < 3 * Cc && c < Csrc) v = W[((size_t)chunk * Csrc + c) * ncol + n];
  u16 h, l;
  split_bf(v, h, l);
  Wh[idx] = h; Wl[idx] = l;
}

// ---------- build XA cols 0..65 (X section), bf16 hi/lo ----------
__global__ __launch_bounds__(256) void k_bxa_full(const float* __restrict__ x,
                                                  const float* __restrict__ ycov,
                                                  const float* __restrict__ go,
                                                  const float* __restrict__ h,
                                                  u16* __restrict__ XAh, u16* __restrict__ XAl,
                                                  int t, int dec) {
  int idx = blockIdx.x * 256 + threadIdx.x;
  if (idx >= NB * Cc) return;
  int row = idx / Cc, c = idx % Cc;
  int n = row >> 6, b = row & 63;
  float v;
  if (dec) {
    if (c == 0) v = go[row];
    else if (c == 1) v = ycov[(size_t)b * TN + t * Nn + n];
    else v = h[(size_t)row * Hc + c - 2];
  } else {
    if (c == 0) v = x[(size_t)b * TN + t * Nn + n];
    else if (c < 65) v = h[(size_t)row * Hc + c - 1];
    else v = 0.f;
  }
  u16 hh, ll;
  split_bf(v, hh, ll);
  size_t a = (size_t)row * SA + c;
  XAh[a] = hh; XAl[a] = ll;
}

// ---------- rewrite XA state cols with z*h ----------
__global__ __launch_bounds__(256) void k_bxa_upd(const float* __restrict__ z,
                                                 const float* __restrict__ h,
                                                 u16* __restrict__ XAh, u16* __restrict__ XAl,
                                                 int off) {
  int idx = blockIdx.x * 256 + threadIdx.x;
  if (idx >= NB * Hc) return;
  int row = idx >> 6, i = idx & 63;
  float v = z[idx] * h[idx];
  u16 hh, ll;
  split_bf(v, hh, ll);
  size_t a = (size_t)row * SA + off + i;
  XAh[a] = hh; XAl[a] = ll;
}

// ---------- build Xt[(b*66+c)][n] bf16 hi/lo via LDS transpose ----------
// mode: 0 enc full, 1 dec full, 2 enc state-only(z*h), 3 dec state-only(z*h)
__global__ __launch_bounds__(256) void k_bxt(const float* __restrict__ x,
                                             const float* __restrict__ ycov,
                                             const float* __restrict__ go,
                                             const float* __restrict__ h,
                                             const float* __restrict__ z,
                                             u16* __restrict__ Xth, u16* __restrict__ Xtl,
                                             int t, int mode) {
  __shared__ float sx[64][67];
  int n0 = blockIdx.x * 64, b = blockIdx.y;
  int tid = threadIdx.x;
  int off = (mode == 0 || mode == 2) ? 1 : 2;
  bool full = mode < 2;
  int hh = tid & 63, nq = tid >> 6;
#pragma unroll
  for (int i = 0; i < 16; i++) {
    int n = nq * 16 + i;
    size_t hidx = ((size_t)(n0 + n) * 64 + b) * Hc + hh;
    float v = h[hidx];
    if (mode >= 2) v *= z[hidx];
    sx[n][off + hh] = v;
  }
  if (full && tid < 64) {
    int n = tid;
    if (mode == 0) {
      sx[n][0] = x[(size_t)b * TN + t * Nn + n0 + n];
      sx[n][65] = 0.f;
    } else {
      sx[n][0] = go[(size_t)(n0 + n) * 64 + b];
      sx[n][1] = ycov[(size_t)b * TN + t * Nn + n0 + n];
    }
  }
  __syncthreads();
  int n = tid & 63, cq = tid >> 6;
  if (full) {
    for (int c = cq; c < Cc; c += 4) {
      u16 vh, vl;
      split_bf(sx[n][c], vh, vl);
      size_t a = ((size_t)b * Cc + c) * Nn + n0 + n;
      Xth[a] = vh; Xtl[a] = vl;
    }
  } else {
    for (int c = cq; c < 64; c += 4) {
      u16 vh, vl;
      split_bf(sx[n][off + c], vh, vl);
      size_t a = ((size_t)b * Cc + off + c) * Nn + n0 + n;
      Xth[a] = vh; Xtl[a] = vl;
    }
  }
}

// ---------- Y1 = S@X, Y2 = S2@X via split-bf16 MFMA; writes into XA cols 66.. ----------
// BM=64 (n-dim), BN=128 (j=(b,c) dim), BK=32. 4 waves 2x2, wave tile 32x64.
__global__ __launch_bounds__(256) void k_ygemm(const u16* __restrict__ S1h, const u16* __restrict__ S1l,
                                               const u16* __restrict__ S2h, const u16* __restrict__ S2l,
                                               const u16* __restrict__ Xth, const u16* __restrict__ Xtl,
                                               u16* __restrict__ XAh, u16* __restrict__ XAl) {
  // LDS: A mats (S1h,S1l,S2h,S2l) 64x32 each = 2048 shorts; B (Xt hi,lo) 128x32 = 4096 shorts
  __shared__ u16 lds[4 * 2048 + 2 * 4096];  // 32 KB
  const int tid = threadIdx.x;
  const int wave = tid >> 6, lane = tid & 63;
  const int i0 = blockIdx.y * 64;
  const int j0 = blockIdx.x * 128;
  const int wy = wave >> 1, wx = wave & 1;
  const int m = lane & 15, quad = lane >> 4;

  f32x4 acc1[2][4], acc2[2][4];
  f32x4 z4 = {0.f, 0.f, 0.f, 0.f};
#pragma unroll
  for (int a = 0; a < 2; a++)
#pragma unroll
    for (int q = 0; q < 4; q++) { acc1[a][q] = z4; acc2[a][q] = z4; }

  // staging coords (swizzled: LDS chunk ci holds (r, kc) with ci = r*4 + (kc^(r&3)))
  const int ar = tid >> 2;
  const int akc = (tid & 3) ^ (ar & 3);
  const u16* amat[4] = {S1h, S1l, S2h, S2l};

  for (int k0 = 0; k0 < Nn; k0 += 32) {
#pragma unroll
    for (int s = 0; s < 4; s++)
      gld16(amat[s] + (size_t)(i0 + ar) * Nn + k0 + akc * 8, &lds[s * 2048 + wave * 512]);
#pragma unroll
    for (int p = 0; p < 2; p++) {
      int r = p * 64 + (tid >> 2);
      int kc = (tid & 3) ^ (r & 3);
      gld16(Xth + (size_t)(j0 + r) * Nn + k0 + kc * 8,
            &lds[8192 + p * 2048 + wave * 512]);
      gld16(Xtl + (size_t)(j0 + r) * Nn + k0 + kc * 8,
            &lds[8192 + 4096 + p * 2048 + wave * 512]);
    }
    __syncthreads();

    bf16x8 a1h[2], a1l[2], a2h[2], a2l[2], bh[4], bl[4];
#pragma unroll
    for (int mb = 0; mb < 2; mb++) {
      int r = wy * 32 + mb * 16 + m;
      int ci = r * 4 + (quad ^ (r & 3));
      a1h[mb] = *(const bf16x8*)&lds[0 * 2048 + ci * 8];
      a1l[mb] = *(const bf16x8*)&lds[1 * 2048 + ci * 8];
      a2h[mb] = *(const bf16x8*)&lds[2 * 2048 + ci * 8];
      a2l[mb] = *(const bf16x8*)&lds[3 * 2048 + ci * 8];
    }
#pragma unroll
    for (int nb = 0; nb < 4; nb++) {
      int rj = wx * 64 + nb * 16 + m;
      int cj = rj * 4 + (quad ^ (rj & 3));
      bh[nb] = *(const bf16x8*)&lds[8192 + cj * 8];
      bl[nb] = *(const bf16x8*)&lds[8192 + 4096 + cj * 8];
    }
#pragma unroll
    for (int mb = 0; mb < 2; mb++)
#pragma unroll
      for (int nb = 0; nb < 4; nb++) {
        acc1[mb][nb] = __builtin_amdgcn_mfma_f32_16x16x32_bf16(a1h[mb], bh[nb], acc1[mb][nb], 0, 0, 0);
        acc1[mb][nb] = __builtin_amdgcn_mfma_f32_16x16x32_bf16(a1h[mb], bl[nb], acc1[mb][nb], 0, 0, 0);
        acc1[mb][nb] = __builtin_amdgcn_mfma_f32_16x16x32_bf16(a1l[mb], bh[nb], acc1[mb][nb], 0, 0, 0);
        acc2[mb][nb] = __builtin_amdgcn_mfma_f32_16x16x32_bf16(a2h[mb], bh[nb], acc2[mb][nb], 0, 0, 0);
        acc2[mb][nb] = __builtin_amdgcn_mfma_f32_16x16x32_bf16(a2h[mb], bl[nb], acc2[mb][nb], 0, 0, 0);
        acc2[mb][nb] = __builtin_amdgcn_mfma_f32_16x16x32_bf16(a2l[mb], bh[nb], acc2[mb][nb], 0, 0, 0);
      }
    __syncthreads();
  }

  // epilogue: D row = i (n-dim), col j = b*66+c; write to XA[(i*64+b)*208 + {66,132}+c]
#pragma unroll
  for (int mb = 0; mb < 2; mb++)
#pragma unroll
    for (int nb = 0; nb < 4; nb++) {
      int col = j0 + wx * 64 + nb * 16 + m;
      int bb = col / Cc, cc = col % Cc;
#pragma unroll
      for (int p = 0; p < 4; p++) {
        int row = i0 + wy * 32 + mb * 16 + quad * 4 + p;
        size_t base = ((size_t)row * 64 + bb) * SA;
        u16 vh, vl;
        split_bf(acc1[mb][nb][p], vh, vl);
        XAh[base + 66 + cc] = vh; XAl[base + 66 + cc] = vl;
        split_bf(acc2[mb][nb][p], vh, vl);
        XAh[base + 132 + cc] = vh; XAl[base + 132 + cc] = vl;
      }
    }
}

// ---------- gate: sigmoid(XA(65536x224) @ Wt^T(224x128) + b) -> Zb, Rb ----------
// BM=128, BN=128, BK=32, K=224; 4 waves 2x2, wave tile 64x64
__global__ __launch_bounds__(256) void k_gate(const u16* __restrict__ XAh, const u16* __restrict__ XAl,
                                              const u16* __restrict__ Wh, const u16* __restrict__ Wl,
                                              const float* __restrict__ bias,
                                              float* __restrict__ Zb, float* __restrict__ Rb) {
  __shared__ u16 lds[4 * 4096];  // Ah, Al (128x32), Bh, Bl (128x32) = 32KB
  const int tid = threadIdx.x;
  const int wave = tid >> 6, lane = tid & 63;
  const int r0 = blockIdx.x * 128;
  const int wy = wave >> 1, wx = wave & 1;
  const int m = lane & 15, quad = lane >> 4;

  f32x4 acc[4][4];
  f32x4 z4 = {0.f, 0.f, 0.f, 0.f};
#pragma unroll
  for (int a = 0; a < 4; a++)
#pragma unroll
    for (int q = 0; q < 4; q++) acc[a][q] = z4;

  for (int kt = 0; kt < 7; kt++) {
    int k0 = kt * 32;
#pragma unroll
    for (int p = 0; p < 2; p++) {
      int r = p * 64 + (tid >> 2);
      int kc = (tid & 3) ^ (r & 3);
      gld16(XAh + (size_t)(r0 + r) * SA + k0 + kc * 8, &lds[p * 2048 + wave * 512]);
      gld16(XAl + (size_t)(r0 + r) * SA + k0 + kc * 8, &lds[4096 + p * 2048 + wave * 512]);
      gld16(Wh + (size_t)r * KP + k0 + kc * 8, &lds[8192 + p * 2048 + wave * 512]);
      gld16(Wl + (size_t)r * KP + k0 + kc * 8, &lds[12288 + p * 2048 + wave * 512]);
    }
    __syncthreads();

    bf16x8 ah[4], al[4], bh[4], bl[4];
#pragma unroll
    for (int mb = 0; mb < 4; mb++) {
      int r = wy * 64 + mb * 16 + m;
      int ci = r * 4 + (quad ^ (r & 3));
      ah[mb] = *(const bf16x8*)&lds[ci * 8];
      al[mb] = *(const bf16x8*)&lds[4096 + ci * 8];
    }
#pragma unroll
    for (int nb = 0; nb < 4; nb++) {
      int rj = wx * 64 + nb * 16 + m;
      int cj = rj * 4 + (quad ^ (rj & 3));
      bh[nb] = *(const bf16x8*)&lds[8192 + cj * 8];
      bl[nb] = *(const bf16x8*)&lds[12288 + cj * 8];
    }
#pragma unroll
    for (int mb = 0; mb < 4; mb++)
#pragma unroll
      for (int nb = 0; nb < 4; nb++) {
        acc[mb][nb] = __builtin_amdgcn_mfma_f32_16x16x32_bf16(ah[mb], bh[nb], acc[mb][nb], 0, 0, 0);
        acc[mb][nb] = __builtin_amdgcn_mfma_f32_16x16x32_bf16(ah[mb], bl[nb], acc[mb][nb], 0, 0, 0);
        acc[mb][nb] = __builtin_amdgcn_mfma_f32_16x16x32_bf16(al[mb], bh[nb], acc[mb][nb], 0, 0, 0);
      }
    __syncthreads();
  }

#pragma unroll
  for (int mb = 0; mb < 4; mb++)
#pragma unroll
    for (int nb = 0; nb < 4; nb++) {
      int col = wx * 64 + nb * 16 + m;
      float bv = bias[col];
#pragma unroll
      for (int p = 0; p < 4; p++) {
        int row = r0 + wy * 64 + mb * 16 + quad * 4 + p;
        float sg = 1.f / (1.f + expf(-(acc[mb][nb][p] + bv)));
        if (col < 64) Zb[(size_t)row * 64 + col] = sg;
        else Rb[(size_t)row * 64 + col - 64] = sg;
      }
    }
}

// ---------- update: hc = tanh(XA' @ Wu^T + b); h = r*h + (1-r)*hc ----------
// BM=128, BN=64, BK=32; 4 waves 2x2, wave tile 64x32
__global__ __launch_bounds__(256) void k_upd(const u16* __restrict__ XAh, const u16* __restrict__ XAl,
                                             const u16* __restrict__ Wh, const u16* __restrict__ Wl,
                                             const float* __restrict__ bias,
                                             const float* __restrict__ Rb,
                                             float* __restrict__ h) {
  __shared__ u16 lds[2 * 4096 + 2 * 2048];  // Ah, Al (128x32), Bh, Bl (64x32) = 24KB
  const int tid = threadIdx.x;
  const int wave = tid >> 6, lane = tid & 63;
  const int r0 = blockIdx.x * 128;
  const int wy = wave >> 1, wx = wave & 1;
  const int m = lane & 15, quad = lane >> 4;

  f32x4 acc[4][2];
  f32x4 z4 = {0.f, 0.f, 0.f, 0.f};
#pragma unroll
  for (int a = 0; a < 4; a++) { acc[a][0] = z4; acc[a][1] = z4; }

  for (int kt = 0; kt < 7; kt++) {
    int k0 = kt * 32;
#pragma unroll
    for (int p = 0; p < 2; p++) {
      int r = p * 64 + (tid >> 2);
      int kc = (tid & 3) ^ (r & 3);
      gld16(XAh + (size_t)(r0 + r) * SA + k0 + kc * 8, &lds[p * 2048 + wave * 512]);
      gld16(XAl + (size_t)(r0 + r) * SA + k0 + kc * 8, &lds[4096 + p * 2048 + wave * 512]);
    }
    {
      int r = tid >> 2;
      int kc = (tid & 3) ^ (r & 3);
      gld16(Wh + (size_t)r * KP + k0 + kc * 8, &lds[8192 + wave * 512]);
      gld16(Wl + (size_t)r * KP + k0 + kc * 8, &lds[10240 + wave * 512]);
    }
    __syncthreads();

    bf16x8 ah[4], al[4], bh[2], bl[2];
#pragma unroll
    for (int mb = 0; mb < 4; mb++) {
      int r = wy * 64 + mb * 16 + m;
      int ci = r * 4 + (quad ^ (r & 3));
      ah[mb] = *(const bf16x8*)&lds[ci * 8];
      al[mb] = *(const bf16x8*)&lds[4096 + ci * 8];
    }
#pragma unroll
    for (int nb = 0; nb < 2; nb++) {
      int rj = wx * 32 + nb * 16 + m;
      int cj = rj * 4 + (quad ^ (rj & 3));
      bh[nb] = *(const bf16x8*)&lds[8192 + cj * 8];
      bl[nb] = *(const bf16x8*)&lds[10240 + cj * 8];
    }
#pragma unroll
    for (int mb = 0; mb < 4; mb++)
#pragma unroll
      for (int nb = 0; nb < 2; nb++) {
        acc[mb][nb] = __builtin_amdgcn_mfma_f32_16x16x32_bf16(ah[mb], bh[nb], acc[mb][nb], 0, 0, 0);
        acc[mb][nb] = __builtin_amdgcn_mfma_f32_16x16x32_bf16(ah[mb], bl[nb], acc[mb][nb], 0, 0, 0);
        acc[mb][nb] = __builtin_amdgcn_mfma_f32_16x16x32_bf16(al[mb], bh[nb], acc[mb][nb], 0, 0, 0);
      }
    __syncthreads();
  }

#pragma unroll
  for (int mb = 0; mb < 4; mb++)
#pragma unroll
    for (int nb = 0; nb < 2; nb++) {
      int col = wx * 32 + nb * 16 + m;
      float bv = bias[col];
#pragma unroll
      for (int p = 0; p < 4; p++) {
        int row = r0 + wy * 64 + mb * 16 + quad * 4 + p;
        float hc = tanhf(acc[mb][nb][p] + bv);
        size_t idx = (size_t)row * 64 + col;
        float rr = Rb[idx];
        h[idx] = rr * h[idx] + (1.f - rr) * hc;
      }
    }
}

// ---------- de[n][b*10+e] = sum_hh h[n][b][hh] * FC[hh][e] ----------
__global__ __launch_bounds__(256) void k_de(const float* __restrict__ h,
                                            const float* __restrict__ fc,
                                            float* __restrict__ de) {
  __shared__ float fcs[Hc * Ec];
  for (int j = threadIdx.x; j < Hc * Ec; j += 256) fcs[j] = fc[j];
  __syncthreads();
  int idx = blockIdx.x * 256 + threadIdx.x;
  if (idx >= Nn * Bc * Ec) return;
  int n = idx / (Bc * Ec);
  int rem = idx % (Bc * Ec);
  int b = rem / Ec, e = rem % Ec;
  const float* hp = h + (size_t)n * (Bc * Hc) + (size_t)b * Hc;
  float acc = 0.f;
#pragma unroll 8
  for (int hh = 0; hh < Hc; hh++) acc = fmaf(hp[hh], fcs[hh * Ec + e], acc);
  de[idx] = acc;
}

// ---------- go init: go[n][b] = x[b][T-1][n][0] ----------
__global__ __launch_bounds__(256) void k_go_init(const float* __restrict__ x,
                                                 float* __restrict__ go) {
  int idx = blockIdx.x * 256 + threadIdx.x;
  if (idx >= NB) return;
  int n = idx >> 6, b = idx & 63;
  go[idx] = x[(size_t)b * TN + (size_t)(Tc - 1) * Nn + n];
}

// ---------- proj: go = h @ pw + pb ; out[b][t][n] = go ----------
__global__ __launch_bounds__(256) void k_proj(const float* __restrict__ h,
                                              const float* __restrict__ pw,
                                              const float* __restrict__ pb,
                                              float* __restrict__ go,
                                              float* __restrict__ out, int t) {
  int idx = blockIdx.x * 256 + threadIdx.x;
  if (idx >= NB) return;
  int n = idx >> 6, b = idx & 63;
  const float* hp = h + (size_t)idx * Hc;
  float acc = pb[0];
#pragma unroll 8
  for (int i = 0; i < Hc; i++) acc = fmaf(hp[i], pw[i], acc);
  go[idx] = acc;
  out[(size_t)b * TN + (size_t)t * Nn + n] = acc;
}

extern "C" void kernel_launch(void* const* d_in, const int* in_sizes, int n_in,
                              void* d_out, int out_size, void* d_ws, size_t ws_size,
                              hipStream_t stream) {
  (void)in_sizes; (void)n_in; (void)out_size; (void)ws_size;
  const float* x    = (const float*)d_in[0];
  const float* ycov = (const float*)d_in[1];
  const float* emb  = (const float*)d_in[2];
  const float* fce  = (const float*)d_in[3];
  const float* egw  = (const float*)d_in[4];
  const float* egb  = (const float*)d_in[5];
  const float* euw  = (const float*)d_in[6];
  const float* eub  = (const float*)d_in[7];
  const float* dgw  = (const float*)d_in[8];
  const float* dgb  = (const float*)d_in[9];
  const float* duw  = (const float*)d_in[10];
  const float* dub  = (const float*)d_in[11];
  const float* pw   = (const float*)d_in[12];
  const float* pb   = (const float*)d_in[13];
  float* out = (float*)d_out;

  char* wsb = (char*)d_ws;
  size_t off = 0;
  auto alloc = [&](size_t bytes) {
    void* p = wsb + off;
    off = (off + bytes + 255) & ~(size_t)255;
    return p;
  };
  float* S1f = (float*)alloc((size_t)Nn * Nn * 4);
  float* S2f = (float*)alloc((size_t)Nn * Nn * 4);
  u16* S1h = (u16*)alloc((size_t)Nn * Nn * 2);
  u16* S1l = (u16*)alloc((size_t)Nn * Nn * 2);
  u16* S2h = (u16*)alloc((size_t)Nn * Nn * 2);
  u16* S2l = (u16*)alloc((size_t)Nn * Nn * 2);
  float* Hst = (float*)alloc((size_t)NB * Hc * 4);
  u16* XAh = (u16*)alloc((size_t)(NB + 4) * SA * 2);
  u16* XAl = (u16*)alloc((size_t)(NB + 4) * SA * 2);
  u16* Xth = (u16*)alloc((size_t)Bc * Cc * Nn * 2);
  u16* Xtl = (u16*)alloc((size_t)Bc * Cc * Nn * 2);
  float* Zb = (float*)alloc((size_t)NB * Hc * 4);
  float* Rb = (float*)alloc((size_t)NB * Hc * 4);
  float* DE = (float*)alloc((size_t)Nn * Bc * Ec * 4);
  float* GO = (float*)alloc((size_t)NB * 4);
  u16* WgeH = (u16*)alloc(128 * KP * 2); u16* WgeL = (u16*)alloc(128 * KP * 2);
  u16* WueH = (u16*)alloc(64 * KP * 2);  u16* WueL = (u16*)alloc(64 * KP * 2);
  u16* WgdH = (u16*)alloc(128 * KP * 2); u16* WgdL = (u16*)alloc(128 * KP * 2);
  u16* WudH = (u16*)alloc(64 * KP * 2);  u16* WudL = (u16*)alloc(64 * KP * 2);

  hipMemsetAsync(Hst, 0, (size_t)NB * Hc * 4, stream);

  k_prep_wt<<<(128 * KP + 255) / 256, 256, 0, stream>>>(egw, 65, 128, WgeH, WgeL);
  k_prep_wt<<<(64 * KP + 255) / 256, 256, 0, stream>>>(euw, 65, 64, WueH, WueL);
  k_prep_wt<<<(128 * KP + 255) / 256, 256, 0, stream>>>(dgw, 66, 128, WgdH, WgdL);
  k_prep_wt<<<(64 * KP + 255) / 256, 256, 0, stream>>>(duw, 66, 64, WudH, WudL);

  k_scores<<<Nn, 256, 0, stream>>>(emb, Ec, S1f);
  k_s2<<<dim3(16, 16), 256, 0, stream>>>(S1f, S2f);
  k_split2<<<(Nn * Nn + 255) / 256, 256, 0, stream>>>(S1f, S2f, S1h, S1l, S2h, S2l);

  const int gBXA = (NB * Cc + 255) / 256;
  const int gUPD = (NB * Hc) / 256;

  for (int t = 0; t < Tc; t++) {
    k_bxa_full<<<gBXA, 256, 0, stream>>>(x, nullptr, nullptr, Hst, XAh, XAl, t, 0);
    k_bxt<<<dim3(16, 64), 256, 0, stream>>>(x, nullptr, nullptr, Hst, nullptr, Xth, Xtl, t, 0);
    k_ygemm<<<dim3(33, 16), 256, 0, stream>>>(S1h, S1l, S2h, S2l, Xth, Xtl, XAh, XAl);
    k_gate<<<512, 256, 0, stream>>>(XAh, XAl, WgeH, WgeL, egb, Zb, Rb);
    k_bxa_upd<<<gUPD, 256, 0, stream>>>(Zb, Hst, XAh, XAl, 1);
    k_bxt<<<dim3(16, 64), 256, 0, stream>>>(x, nullptr, nullptr, Hst, Zb, Xth, Xtl, t, 2);
    k_ygemm<<<dim3(33, 16), 256, 0, stream>>>(S1h, S1l, S2h, S2l, Xth, Xtl, XAh, XAl);
    k_upd<<<512, 256, 0, stream>>>(XAh, XAl, WueH, WueL, eub, Rb, Hst);
  }

  k_de<<<(Nn * Bc * Ec + 255) / 256, 256, 0, stream>>>(Hst, fce, DE);
  k_scores<<<Nn, 256, 0, stream>>>(DE, Bc * Ec, S1f);
  k_s2<<<dim3(16, 16), 256, 0, stream>>>(S1f, S2f);
  k_split2<<<(Nn * Nn + 255) / 256, 256, 0, stream>>>(S1f, S2f, S1h, S1l, S2h, S2l);
  k_go_init<<<NB / 256, 256, 0, stream>>>(x, GO);

  for (int t = 0; t < Tc; t++) {
    k_bxa_full<<<gBXA, 256, 0, stream>>>(nullptr, ycov, GO, Hst, XAh, XAl, t, 1);
    k_bxt<<<dim3(16, 64), 256, 0, stream>>>(nullptr, ycov, GO, Hst, nullptr, Xth, Xtl, t, 1);
    k_ygemm<<<dim3(33, 16), 256, 0, stream>>>(S1h, S1l, S2h, S2l, Xth, Xtl, XAh, XAl);
    k_gate<<<512, 256, 0, stream>>>(XAh, XAl, WgdH, WgdL, dgb, Zb, Rb);
    k_bxa_upd<<<gUPD, 256, 0, stream>>>(Zb, Hst, XAh, XAl, 2);
    k_bxt<<<dim3(16, 64), 256, 0, stream>>>(nullptr, ycov, GO, Hst, Zb, Xth, Xtl, t, 3);
    k_ygemm<<<dim3(33, 16), 256, 0, stream>>>(S1h, S1l, S2h, S2l, Xth, Xtl, XAh, XAl);
    k_upd<<<512, 256, 0, stream>>>(XAh, XAl, WudH, WudL, dub, Rb, Hst);
    k_proj<<<NB / 256, 256, 0, stream>>>(Hst, pw, pb, GO, out, t);
  }
}

// Round 3
// 7037.292 us; speedup vs baseline: 4.8880x; 1.0577x over previous
//
#include <hip/hip_runtime.h>
#include <math.h>

typedef __attribute__((ext_vector_type(8))) short bf16x8;
typedef __attribute__((ext_vector_type(4))) float f32x4;
typedef unsigned short u16;

namespace {
constexpr int Bc = 64, Tc = 12, Nn = 1024, Hc = 64, Ec = 10;
constexpr int NB = Nn * Bc;  // 65536
constexpr int Cc = 66;       // unified channel count (enc uses 65, col 65 zeroed)
constexpr int SA = 208;      // XA row stride ([X(66)|Y1(66)|Y2(66)|pad10])
constexpr int KP = 224;      // padded K for gate/update GEMMs (7 x 32)
constexpr int TN = Tc * Nn;  // 12288
}

// bank-group swizzle: chunk (r,kc) stored at 16B-unit ci = r*4 + (kc ^ SWZ(r))
// SWZ(r)=(r>>1)&3 makes ci%8 = 4*(r&1) + ((r>>1)&3): all 8 groups per 8 rows -> 2-way (free)
#define SWZ(r) (((r) >> 1) & 3)

__device__ __forceinline__ void gld16(const void* g, void* l) {
  __builtin_amdgcn_global_load_lds(
      (const __attribute__((address_space(1))) void*)g,
      (__attribute__((address_space(3))) void*)l, 16, 0, 0);
}

// split fp32 -> bf16 hi + bf16 lo (RNE both)
__device__ __forceinline__ void split_bf(float v, u16& h, u16& l) {
  unsigned u = __float_as_uint(v);
  unsigned hu = (u + 0x7FFFu + ((u >> 16) & 1u)) & 0xFFFF0000u;
  h = (u16)(hu >> 16);
  float r = v - __uint_as_float(hu);
  unsigned u2 = __float_as_uint(r);
  l = (u16)((u2 + 0x7FFFu + ((u2 >> 16) & 1u)) >> 16);
}

// ---------- G = in @ in^T (fp32, tiled, coalesced) ----------
__global__ __launch_bounds__(256) void k_gram(const float* __restrict__ in, int Kd,
                                              float* __restrict__ G) {
  __shared__ float At[16][64];
  __shared__ float Bt[16][64];
  int i0 = blockIdx.y * 64, j0 = blockIdx.x * 64;
  int tx = threadIdx.x & 15, ty = threadIdx.x >> 4;
  float acc[4][4] = {};
  for (int k0 = 0; k0 < Kd; k0 += 16) {
    for (int u = threadIdx.x; u < 1024; u += 256) {
      int i = u >> 4, k = u & 15;
      At[k][i] = (k0 + k < Kd) ? in[(size_t)(i0 + i) * Kd + k0 + k] : 0.f;
    }
    for (int u = threadIdx.x; u < 1024; u += 256) {
      int j = u >> 4, k = u & 15;
      Bt[k][j] = (k0 + k < Kd) ? in[(size_t)(j0 + j) * Kd + k0 + k] : 0.f;
    }
    __syncthreads();
#pragma unroll
    for (int kk = 0; kk < 16; kk++) {
      float a[4], b[4];
#pragma unroll
      for (int p = 0; p < 4; p++) a[p] = At[kk][ty * 4 + p];
#pragma unroll
      for (int q = 0; q < 4; q++) b[q] = Bt[kk][tx * 4 + q];
#pragma unroll
      for (int p = 0; p < 4; p++)
#pragma unroll
        for (int q = 0; q < 4; q++) acc[p][q] = fmaf(a[p], b[q], acc[p][q]);
    }
    __syncthreads();
  }
  for (int p = 0; p < 4; p++)
    for (int q = 0; q < 4; q++)
      G[(size_t)(i0 + ty * 4 + p) * Nn + j0 + tx * 4 + q] = acc[p][q];
}

// ---------- S = row_softmax(relu(G)) ----------
__global__ __launch_bounds__(256) void k_softmax(const float* __restrict__ G,
                                                 float* __restrict__ S) {
  __shared__ float sred[8];
  int n = blockIdx.x;
  float v[4];
#pragma unroll
  for (int i = 0; i < 4; i++)
    v[i] = fmaxf(G[(size_t)n * Nn + threadIdx.x + i * 256], 0.f);
  float mx = fmaxf(fmaxf(v[0], v[1]), fmaxf(v[2], v[3]));
  for (int off = 32; off > 0; off >>= 1) mx = fmaxf(mx, __shfl_down(mx, off));
  if ((threadIdx.x & 63) == 0) sred[threadIdx.x >> 6] = mx;
  __syncthreads();
  float rmax = fmaxf(fmaxf(sred[0], sred[1]), fmaxf(sred[2], sred[3]));
  float s = 0.f;
#pragma unroll
  for (int i = 0; i < 4; i++) { v[i] = expf(v[i] - rmax); s += v[i]; }
  for (int off = 32; off > 0; off >>= 1) s += __shfl_down(s, off);
  if ((threadIdx.x & 63) == 0) sred[4 + (threadIdx.x >> 6)] = s;
  __syncthreads();
  float inv = 1.f / (sred[4] + sred[5] + sred[6] + sred[7]);
#pragma unroll
  for (int i = 0; i < 4; i++) S[(size_t)n * Nn + threadIdx.x + i * 256] = v[i] * inv;
}

// ---------- S2 = 2*S@S - I (fp32, 2 dispatches total) ----------
__global__ __launch_bounds__(256) void k_s2(const float* __restrict__ S,
                                            float* __restrict__ S2) {
  __shared__ float At[16][64];
  __shared__ float Bt[16][64];
  int i0 = blockIdx.y * 64, j0 = blockIdx.x * 64;
  int tx = threadIdx.x & 15, ty = threadIdx.x >> 4;
  float acc[4][4] = {};
  for (int k0 = 0; k0 < Nn; k0 += 16) {
    for (int u = threadIdx.x; u < 1024; u += 256) {
      int i = u >> 4, k = u & 15;
      At[k][i] = S[(size_t)(i0 + i) * Nn + k0 + k];
    }
    for (int u = threadIdx.x; u < 1024; u += 256) {
      int k = u >> 6, j = u & 63;
      Bt[k][j] = S[(size_t)(k0 + k) * Nn + j0 + j];
    }
    __syncthreads();
#pragma unroll
    for (int kk = 0; kk < 16; kk++) {
      float a[4], b[4];
#pragma unroll
      for (int p = 0; p < 4; p++) a[p] = At[kk][ty * 4 + p];
#pragma unroll
      for (int q = 0; q < 4; q++) b[q] = Bt[kk][tx * 4 + q];
#pragma unroll
      for (int p = 0; p < 4; p++)
#pragma unroll
        for (int q = 0; q < 4; q++) acc[p][q] = fmaf(a[p], b[q], acc[p][q]);
    }
    __syncthreads();
  }
  for (int p = 0; p < 4; p++)
    for (int q = 0; q < 4; q++) {
      int i = i0 + ty * 4 + p, j = j0 + tx * 4 + q;
      S2[(size_t)i * Nn + j] = 2.f * acc[p][q] - (i == j ? 1.f : 0.f);
    }
}

// ---------- split S1,S2 fp32 -> bf16 hi/lo ----------
__global__ __launch_bounds__(256) void k_split2(const float* __restrict__ A,
                                                const float* __restrict__ B,
                                                u16* __restrict__ Ah, u16* __restrict__ Al,
                                                u16* __restrict__ Bh, u16* __restrict__ Bl) {
  int i = blockIdx.x * 256 + threadIdx.x;
  if (i >= Nn * Nn) return;
  u16 h, l;
  split_bf(A[i], h, l); Ah[i] = h; Al[i] = l;
  split_bf(B[i], h, l); Bh[i] = h; Bl[i] = l;
}

// ---------- Wt prep: Wt[n][kpad] hi/lo, kpad = chunk*66 + c; zeros for pad ----------
__global__ __launch_bounds__(256) void k_prep_wt(const float* __restrict__ W, int Csrc,
                                                 int ncol, u16* __restrict__ Wh,
                                                 u16* __restrict__ Wl) {
  int idx = blockIdx.x * 256 + threadIdx.x;
  if (idx >= ncol * KP) return;
  int n = idx / KP, kp = idx % KP;
  int chunk = kp / Cc, c = kp % Cc;
  float v = 0.f;
  if (kp < 3 * Cc && c < Csrc) v = W[((size_t)chunk * Csrc + c) * ncol + n];
  u16 h, l;
  split_bf(v, h, l);
  Wh[idx] = h; Wl[idx] = l;
}

// ---------- fill XA col0 = x_t (enc) ----------
__global__ __launch_bounds__(256) void k_fill_enc(const float* __restrict__ x,
                                                  u16* __restrict__ XAh, u16* __restrict__ XAl,
                                                  int t) {
  int idx = blockIdx.x * 256 + threadIdx.x;
  if (idx >= NB) return;
  int n = idx >> 6, b = idx & 63;
  u16 h, l;
  split_bf(x[(size_t)b * TN + t * Nn + n], h, l);
  XAh[(size_t)idx * SA] = h; XAl[(size_t)idx * SA] = l;
}

// ---------- fill XA col0 = go, col1 = ycov_t (dec) ----------
__global__ __launch_bounds__(256) void k_fill_dec(const float* __restrict__ go,
                                                  const float* __restrict__ ycov,
                                                  u16* __restrict__ XAh, u16* __restrict__ XAl,
                                                  int t) {
  int idx = blockIdx.x * 256 + threadIdx.x;
  if (idx >= NB) return;
  int n = idx >> 6, b = idx & 63;
  u16 h, l;
  split_bf(go[idx], h, l);
  XAh[(size_t)idx * SA] = h; XAl[(size_t)idx * SA] = l;
  split_bf(ycov[(size_t)b * TN + t * Nn + n], h, l);
  XAh[(size_t)idx * SA + 1] = h; XAl[(size_t)idx * SA + 1] = l;
}

// ---------- full Xt build: Xt[(b*66+c)][n] from x/go/ycov/h  (mode 0 enc, 1 dec) ----------
__global__ __launch_bounds__(256) void k_bxt(const float* __restrict__ x,
                                             const float* __restrict__ ycov,
                                             const float* __restrict__ go,
                                             const float* __restrict__ h,
                                             u16* __restrict__ Xth, u16* __restrict__ Xtl,
                                             int t, int mode) {
  __shared__ float sx[64][67];
  int n0 = blockIdx.x * 64, b = blockIdx.y;
  int tid = threadIdx.x;
  int off = (mode == 0) ? 1 : 2;
  int hh = tid & 63, nq = tid >> 6;
#pragma unroll
  for (int i = 0; i < 16; i++) {
    int n = nq * 16 + i;
    sx[n][off + hh] = h[((size_t)(n0 + n) * 64 + b) * Hc + hh];
  }
  if (tid < 64) {
    int n = tid;
    if (mode == 0) {
      sx[n][0] = x[(size_t)b * TN + t * Nn + n0 + n];
      sx[n][65] = 0.f;
    } else {
      sx[n][0] = go[(size_t)(n0 + n) * 64 + b];
      sx[n][1] = ycov[(size_t)b * TN + t * Nn + n0 + n];
    }
  }
  __syncthreads();
  int n = tid & 63, cq = tid >> 6;
  for (int c = cq; c < Cc; c += 4) {
    u16 vh, vl;
    split_bf(sx[n][c], vh, vl);
    size_t a = ((size_t)b * Cc + c) * Nn + n0 + n;
    Xth[a] = vh; Xtl[a] = vl;
  }
}

// ---------- state Xt update: transpose XA state cols (already z*h) into Xt ----------
__global__ __launch_bounds__(256) void k_bxt_state(const u16* __restrict__ XAh,
                                                   const u16* __restrict__ XAl,
                                                   u16* __restrict__ Xth, u16* __restrict__ Xtl,
                                                   int off) {
  __shared__ u16 sh[64][66];
  __shared__ u16 sl[64][66];
  int n0 = blockIdx.x * 64, b = blockIdx.y;
  int tid = threadIdx.x;
  for (int u = tid; u < 4096; u += 256) {
    int i = u >> 6, c = u & 63;
    size_t a = ((size_t)(n0 + i) * 64 + b) * SA + off + c;
    sh[i][c] = XAh[a];
    sl[i][c] = XAl[a];
  }
  __syncthreads();
  for (int u = tid; u < 4096; u += 256) {
    int c = u >> 6, i = u & 63;
    size_t a = ((size_t)b * Cc + off + c) * Nn + n0 + i;
    Xth[a] = sh[i][c];
    Xtl[a] = sl[i][c];
  }
}

// ---------- Y1 = S@X, Y2 = S2@X via split-bf16 MFMA; writes into XA cols 66.. ----------
// BM=64 (n), BN=128 (j=(b,c)), BK=32; 4 waves 2x2, wave tile 32x64
__global__ __launch_bounds__(256) void k_ygemm(const u16* __restrict__ S1h, const u16* __restrict__ S1l,
                                               const u16* __restrict__ S2h, const u16* __restrict__ S2l,
                                               const u16* __restrict__ Xth, const u16* __restrict__ Xtl,
                                               u16* __restrict__ XAh, u16* __restrict__ XAl) {
  __shared__ u16 lds[4 * 2048 + 2 * 4096];  // 32 KB
  const int tid = threadIdx.x;
  const int wave = tid >> 6, lane = tid & 63;
  const int i0 = blockIdx.y * 64;
  const int j0 = blockIdx.x * 128;
  const int wy = wave >> 1, wx = wave & 1;
  const int m = lane & 15, quad = lane >> 4;

  f32x4 acc1[2][4], acc2[2][4];
  f32x4 z4 = {0.f, 0.f, 0.f, 0.f};
#pragma unroll
  for (int a = 0; a < 2; a++)
#pragma unroll
    for (int q = 0; q < 4; q++) { acc1[a][q] = z4; acc2[a][q] = z4; }

  const int ar = tid >> 2;
  const int akc = (tid & 3) ^ SWZ(ar);
  const u16* amat[4] = {S1h, S1l, S2h, S2l};

  for (int k0 = 0; k0 < Nn; k0 += 32) {
#pragma unroll
    for (int s = 0; s < 4; s++)
      gld16(amat[s] + (size_t)(i0 + ar) * Nn + k0 + akc * 8, &lds[s * 2048 + wave * 512]);
#pragma unroll
    for (int p = 0; p < 2; p++) {
      int r = p * 64 + (tid >> 2);
      int kc = (tid & 3) ^ SWZ(r);
      gld16(Xth + (size_t)(j0 + r) * Nn + k0 + kc * 8, &lds[8192 + p * 2048 + wave * 512]);
      gld16(Xtl + (size_t)(j0 + r) * Nn + k0 + kc * 8, &lds[12288 + p * 2048 + wave * 512]);
    }
    __syncthreads();

    bf16x8 a1h[2], a1l[2], a2h[2], a2l[2], bh[4], bl[4];
#pragma unroll
    for (int mb = 0; mb < 2; mb++) {
      int r = wy * 32 + mb * 16 + m;
      int ci = r * 4 + (quad ^ SWZ(r));
      a1h[mb] = *(const bf16x8*)&lds[0 * 2048 + ci * 8];
      a1l[mb] = *(const bf16x8*)&lds[1 * 2048 + ci * 8];
      a2h[mb] = *(const bf16x8*)&lds[2 * 2048 + ci * 8];
      a2l[mb] = *(const bf16x8*)&lds[3 * 2048 + ci * 8];
    }
#pragma unroll
    for (int nb = 0; nb < 4; nb++) {
      int rj = wx * 64 + nb * 16 + m;
      int cj = rj * 4 + (quad ^ SWZ(rj));
      bh[nb] = *(const bf16x8*)&lds[8192 + cj * 8];
      bl[nb] = *(const bf16x8*)&lds[12288 + cj * 8];
    }
#pragma unroll
    for (int mb = 0; mb < 2; mb++)
#pragma unroll
      for (int nb = 0; nb < 4; nb++) {
        acc1[mb][nb] = __builtin_amdgcn_mfma_f32_16x16x32_bf16(a1h[mb], bh[nb], acc1[mb][nb], 0, 0, 0);
        acc1[mb][nb] = __builtin_amdgcn_mfma_f32_16x16x32_bf16(a1h[mb], bl[nb], acc1[mb][nb], 0, 0, 0);
        acc1[mb][nb] = __builtin_amdgcn_mfma_f32_16x16x32_bf16(a1l[mb], bh[nb], acc1[mb][nb], 0, 0, 0);
        acc2[mb][nb] = __builtin_amdgcn_mfma_f32_16x16x32_bf16(a2h[mb], bh[nb], acc2[mb][nb], 0, 0, 0);
        acc2[mb][nb] = __builtin_amdgcn_mfma_f32_16x16x32_bf16(a2h[mb], bl[nb], acc2[mb][nb], 0, 0, 0);
        acc2[mb][nb] = __builtin_amdgcn_mfma_f32_16x16x32_bf16(a2l[mb], bh[nb], acc2[mb][nb], 0, 0, 0);
      }
    __syncthreads();
  }

#pragma unroll
  for (int mb = 0; mb < 2; mb++)
#pragma unroll
    for (int nb = 0; nb < 4; nb++) {
      int col = j0 + wx * 64 + nb * 16 + m;
      int bb = col / Cc, cc = col % Cc;
#pragma unroll
      for (int p = 0; p < 4; p++) {
        int row = i0 + wy * 32 + mb * 16 + quad * 4 + p;
        size_t base = ((size_t)row * 64 + bb) * SA;
        u16 vh, vl;
        split_bf(acc1[mb][nb][p], vh, vl);
        XAh[base + 66 + cc] = vh; XAl[base + 66 + cc] = vl;
        split_bf(acc2[mb][nb][p], vh, vl);
        XAh[base + 132 + cc] = vh; XAl[base + 132 + cc] = vl;
      }
    }
}

// ---------- gate: sigmoid(XA @ Wt^T + b) -> Rb; z*h fused into XA state cols ----------
// BM=128, BN=128, BK=32, K=224
__global__ __launch_bounds__(256) void k_gate(const u16* __restrict__ XAh, const u16* __restrict__ XAl,
                                              const u16* __restrict__ Wh, const u16* __restrict__ Wl,
                                              const float* __restrict__ bias,
                                              const float* __restrict__ hst,
                                              float* __restrict__ Rb,
                                              u16* __restrict__ XAho, u16* __restrict__ XAlo,
                                              int off) {
  __shared__ u16 lds[4 * 4096];  // 32KB
  const int tid = threadIdx.x;
  const int wave = tid >> 6, lane = tid & 63;
  const int r0 = blockIdx.x * 128;
  const int wy = wave >> 1, wx = wave & 1;
  const int m = lane & 15, quad = lane >> 4;

  f32x4 acc[4][4];
  f32x4 z4 = {0.f, 0.f, 0.f, 0.f};
#pragma unroll
  for (int a = 0; a < 4; a++)
#pragma unroll
    for (int q = 0; q < 4; q++) acc[a][q] = z4;

  for (int kt = 0; kt < 7; kt++) {
    int k0 = kt * 32;
#pragma unroll
    for (int p = 0; p < 2; p++) {
      int r = p * 64 + (tid >> 2);
      int kc = (tid & 3) ^ SWZ(r);
      gld16(XAh + (size_t)(r0 + r) * SA + k0 + kc * 8, &lds[p * 2048 + wave * 512]);
      gld16(XAl + (size_t)(r0 + r) * SA + k0 + kc * 8, &lds[4096 + p * 2048 + wave * 512]);
      gld16(Wh + (size_t)r * KP + k0 + kc * 8, &lds[8192 + p * 2048 + wave * 512]);
      gld16(Wl + (size_t)r * KP + k0 + kc * 8, &lds[12288 + p * 2048 + wave * 512]);
    }
    __syncthreads();

    bf16x8 ah[4], al[4], bh[4], bl[4];
#pragma unroll
    for (int mb = 0; mb < 4; mb++) {
      int r = wy * 64 + mb * 16 + m;
      int ci = r * 4 + (quad ^ SWZ(r));
      ah[mb] = *(const bf16x8*)&lds[ci * 8];
      al[mb] = *(const bf16x8*)&lds[4096 + ci * 8];
    }
#pragma unroll
    for (int nb = 0; nb < 4; nb++) {
      int rj = wx * 64 + nb * 16 + m;
      int cj = rj * 4 + (quad ^ SWZ(rj));
      bh[nb] = *(const bf16x8*)&lds[8192 + cj * 8];
      bl[nb] = *(const bf16x8*)&lds[12288 + cj * 8];
    }
#pragma unroll
    for (int mb = 0; mb < 4; mb++)
#pragma unroll
      for (int nb = 0; nb < 4; nb++) {
        acc[mb][nb] = __builtin_amdgcn_mfma_f32_16x16x32_bf16(ah[mb], bh[nb], acc[mb][nb], 0, 0, 0);
        acc[mb][nb] = __builtin_amdgcn_mfma_f32_16x16x32_bf16(ah[mb], bl[nb], acc[mb][nb], 0, 0, 0);
        acc[mb][nb] = __builtin_amdgcn_mfma_f32_16x16x32_bf16(al[mb], bh[nb], acc[mb][nb], 0, 0, 0);
      }
    __syncthreads();
  }

#pragma unroll
  for (int mb = 0; mb < 4; mb++)
#pragma unroll
    for (int nb = 0; nb < 4; nb++) {
      int col = wx * 64 + nb * 16 + m;
      float bv = bias[col];
#pragma unroll
      for (int p = 0; p < 4; p++) {
        int row = r0 + wy * 64 + mb * 16 + quad * 4 + p;
        float sg = 1.f / (1.f + expf(-(acc[mb][nb][p] + bv)));
        if (col < 64) {
          // z: write z*h into XA state cols (bf16 hi/lo)
          float v = sg * hst[(size_t)row * 64 + col];
          u16 vh, vl;
          split_bf(v, vh, vl);
          size_t a = (size_t)row * SA + off + col;
          XAho[a] = vh; XAlo[a] = vl;
        } else {
          Rb[(size_t)row * 64 + col - 64] = sg;
        }
      }
    }
}

// ---------- update: hc = tanh(XA' @ Wu^T + b); h = r*h + (1-r)*hc; h -> XA state ----------
// BM=128, BN=64, BK=32
__global__ __launch_bounds__(256) void k_upd(const u16* __restrict__ XAh, const u16* __restrict__ XAl,
                                             const u16* __restrict__ Wh, const u16* __restrict__ Wl,
                                             const float* __restrict__ bias,
                                             const float* __restrict__ Rb,
                                             float* __restrict__ h,
                                             u16* __restrict__ XAho, u16* __restrict__ XAlo,
                                             int off_next) {
  __shared__ u16 lds[2 * 4096 + 2 * 2048];  // 24KB
  const int tid = threadIdx.x;
  const int wave = tid >> 6, lane = tid & 63;
  const int r0 = blockIdx.x * 128;
  const int wy = wave >> 1, wx = wave & 1;
  const int m = lane & 15, quad = lane >> 4;

  f32x4 acc[4][2];
  f32x4 z4 = {0.f, 0.f, 0.f, 0.f};
#pragma unroll
  for (int a = 0; a < 4; a++) { acc[a][0] = z4; acc[a][1] = z4; }

  for (int kt = 0; kt < 7; kt++) {
    int k0 = kt * 32;
#pragma unroll
    for (int p = 0; p < 2; p++) {
      int r = p * 64 + (tid >> 2);
      int kc = (tid & 3) ^ SWZ(r);
      gld16(XAh + (size_t)(r0 + r) * SA + k0 + kc * 8, &lds[p * 2048 + wave * 512]);
      gld16(XAl + (size_t)(r0 + r) * SA + k0 + kc * 8, &lds[4096 + p * 2048 + wave * 512]);
    }
    {
      int r = tid >> 2;
      int kc = (tid & 3) ^ SWZ(r);
      gld16(Wh + (size_t)r * KP + k0 + kc * 8, &lds[8192 + wave * 512]);
      gld16(Wl + (size_t)r * KP + k0 + kc * 8, &lds[10240 + wave * 512]);
    }
    __syncthreads();

    bf16x8 ah[4], al[4], bh[2], bl[2];
#pragma unroll
    for (int mb = 0; mb < 4; mb++) {
      int r = wy * 64 + mb * 16 + m;
      int ci = r * 4 + (quad ^ SWZ(r));
      ah[mb] = *(const bf16x8*)&lds[ci * 8];
      al[mb] = *(const bf16x8*)&lds[4096 + ci * 8];
    }
#pragma unroll
    for (int nb = 0; nb < 2; nb++) {
      int rj = wx * 32 + nb * 16 + m;
      int cj = rj * 4 + (quad ^ SWZ(rj));
      bh[nb] = *(const bf16x8*)&lds[8192 + cj * 8];
      bl[nb] = *(const bf16x8*)&lds[10240 + cj * 8];
    }
#pragma unroll
    for (int mb = 0; mb < 4; mb++)
#pragma unroll
      for (int nb = 0; nb < 2; nb++) {
        acc[mb][nb] = __builtin_amdgcn_mfma_f32_16x16x32_bf16(ah[mb], bh[nb], acc[mb][nb], 0, 0, 0);
        acc[mb][nb] = __builtin_amdgcn_mfma_f32_16x16x32_bf16(ah[mb], bl[nb], acc[mb][nb], 0, 0, 0);
        acc[mb][nb] = __builtin_amdgcn_mfma_f32_16x16x32_bf16(al[mb], bh[nb], acc[mb][nb], 0, 0, 0);
      }
    __syncthreads();
  }

#pragma unroll
  for (int mb = 0; mb < 4; mb++)
#pragma unroll
    for (int nb = 0; nb < 2; nb++) {
      int col = wx * 32 + nb * 16 + m;
      float bv = bias[col];
#pragma unroll
      for (int p = 0; p < 4; p++) {
        int row = r0 + wy * 64 + mb * 16 + quad * 4 + p;
        float hc = tanhf(acc[mb][nb][p] + bv);
        size_t idx = (size_t)row * 64 + col;
        float rr = Rb[idx];
        float hn = rr * h[idx] + (1.f - rr) * hc;
        h[idx] = hn;
        u16 vh, vl;
        split_bf(hn, vh, vl);
        size_t a = (size_t)row * SA + off_next + col;
        XAho[a] = vh; XAlo[a] = vl;
      }
    }
}

// ---------- de[n][b*10+e] = sum_hh h[n][b][hh] * FC[hh][e] ----------
__global__ __launch_bounds__(256) void k_de(const float* __restrict__ h,
                                            const float* __restrict__ fc,
                                            float* __restrict__ de) {
  __shared__ float fcs[Hc * Ec];
  for (int j = threadIdx.x; j < Hc * Ec; j += 256) fcs[j] = fc[j];
  __syncthreads();
  int idx = blockIdx.x * 256 + threadIdx.x;
  if (idx >= Nn * Bc * Ec) return;
  int n = idx / (Bc * Ec);
  int rem = idx % (Bc * Ec);
  int b = rem / Ec, e = rem % Ec;
  const float* hp = h + (size_t)n * (Bc * Hc) + (size_t)b * Hc;
  float acc = 0.f;
#pragma unroll 8
  for (int hh = 0; hh < Hc; hh++) acc = fmaf(hp[hh], fcs[hh * Ec + e], acc);
  de[idx] = acc;
}

// ---------- go init ----------
__global__ __launch_bounds__(256) void k_go_init(const float* __restrict__ x,
                                                 float* __restrict__ go) {
  int idx = blockIdx.x * 256 + threadIdx.x;
  if (idx >= NB) return;
  int n = idx >> 6, b = idx & 63;
  go[idx] = x[(size_t)b * TN + (size_t)(Tc - 1) * Nn + n];
}

// ---------- proj: go = h @ pw + pb ; out[b][t][n] = go ----------
__global__ __launch_bounds__(256) void k_proj(const float* __restrict__ h,
                                              const float* __restrict__ pw,
                                              const float* __restrict__ pb,
                                              float* __restrict__ go,
                                              float* __restrict__ out, int t) {
  int idx = blockIdx.x * 256 + threadIdx.x;
  if (idx >= NB) return;
  int n = idx >> 6, b = idx & 63;
  const float* hp = h + (size_t)idx * Hc;
  float acc = pb[0];
#pragma unroll 8
  for (int i = 0; i < Hc; i++) acc = fmaf(hp[i], pw[i], acc);
  go[idx] = acc;
  out[(size_t)b * TN + (size_t)t * Nn + n] = acc;
}

extern "C" void kernel_launch(void* const* d_in, const int* in_sizes, int n_in,
                              void* d_out, int out_size, void* d_ws, size_t ws_size,
                              hipStream_t stream) {
  (void)in_sizes; (void)n_in; (void)out_size; (void)ws_size;
  const float* x    = (const float*)d_in[0];
  const float* ycov = (const float*)d_in[1];
  const float* emb  = (const float*)d_in[2];
  const float* fce  = (const float*)d_in[3];
  const float* egw  = (const float*)d_in[4];
  const float* egb  = (const float*)d_in[5];
  const float* euw  = (const float*)d_in[6];
  const float* eub  = (const float*)d_in[7];
  const float* dgw  = (const float*)d_in[8];
  const float* dgb  = (const float*)d_in[9];
  const float* duw  = (const float*)d_in[10];
  const float* dub  = (const float*)d_in[11];
  const float* pw   = (const float*)d_in[12];
  const float* pb   = (const float*)d_in[13];
  float* out = (float*)d_out;

  char* wsb = (char*)d_ws;
  size_t off = 0;
  auto alloc = [&](size_t bytes) {
    void* p = wsb + off;
    off = (off + bytes + 255) & ~(size_t)255;
    return p;
  };
  float* S1f = (float*)alloc((size_t)Nn * Nn * 4);
  float* S2f = (float*)alloc((size_t)Nn * Nn * 4);
  u16* S1h = (u16*)alloc((size_t)Nn * Nn * 2);
  u16* S1l = (u16*)alloc((size_t)Nn * Nn * 2);
  u16* S2h = (u16*)alloc((size_t)Nn * Nn * 2);
  u16* S2l = (u16*)alloc((size_t)Nn * Nn * 2);
  float* Hst = (float*)alloc((size_t)NB * Hc * 4);
  u16* XAh = (u16*)alloc((size_t)(NB + 4) * SA * 2);
  u16* XAl = (u16*)alloc((size_t)(NB + 4) * SA * 2);
  u16* Xth = (u16*)alloc((size_t)Bc * Cc * Nn * 2);
  u16* Xtl = (u16*)alloc((size_t)Bc * Cc * Nn * 2);
  float* Rb = (float*)alloc((size_t)NB * Hc * 4);
  float* DE = (float*)alloc((size_t)Nn * Bc * Ec * 4);
  float* GO = (float*)alloc((size_t)NB * 4);
  u16* WgeH = (u16*)alloc(128 * KP * 2); u16* WgeL = (u16*)alloc(128 * KP * 2);
  u16* WueH = (u16*)alloc(64 * KP * 2);  u16* WueL = (u16*)alloc(64 * KP * 2);
  u16* WgdH = (u16*)alloc(128 * KP * 2); u16* WgdL = (u16*)alloc(128 * KP * 2);
  u16* WudH = (u16*)alloc(64 * KP * 2);  u16* WudL = (u16*)alloc(64 * KP * 2);

  hipMemsetAsync(Hst, 0, (size_t)NB * Hc * 4, stream);
  hipMemsetAsync(XAh, 0, (size_t)(NB + 4) * SA * 2, stream);
  hipMemsetAsync(XAl, 0, (size_t)(NB + 4) * SA * 2, stream);

  k_prep_wt<<<(128 * KP + 255) / 256, 256, 0, stream>>>(egw, 65, 128, WgeH, WgeL);
  k_prep_wt<<<(64 * KP + 255) / 256, 256, 0, stream>>>(euw, 65, 64, WueH, WueL);
  k_prep_wt<<<(128 * KP + 255) / 256, 256, 0, stream>>>(dgw, 66, 128, WgdH, WgdL);
  k_prep_wt<<<(64 * KP + 255) / 256, 256, 0, stream>>>(duw, 66, 64, WudH, WudL);

  // encoder supports
  k_gram<<<dim3(16, 16), 256, 0, stream>>>(emb, Ec, S2f);
  k_softmax<<<Nn, 256, 0, stream>>>(S2f, S1f);
  k_s2<<<dim3(16, 16), 256, 0, stream>>>(S1f, S2f);
  k_split2<<<(Nn * Nn + 255) / 256, 256, 0, stream>>>(S1f, S2f, S1h, S1l, S2h, S2l);

  const int gNB = NB / 256;

  for (int t = 0; t < Tc; t++) {
    k_fill_enc<<<gNB, 256, 0, stream>>>(x, XAh, XAl, t);
    k_bxt<<<dim3(16, 64), 256, 0, stream>>>(x, nullptr, nullptr, Hst, Xth, Xtl, t, 0);
    k_ygemm<<<dim3(33, 16), 256, 0, stream>>>(S1h, S1l, S2h, S2l, Xth, Xtl, XAh, XAl);
    k_gate<<<512, 256, 0, stream>>>(XAh, XAl, WgeH, WgeL, egb, Hst, Rb, XAh, XAl, 1);
    k_bxt_state<<<dim3(16, 64), 256, 0, stream>>>(XAh, XAl, Xth, Xtl, 1);
    k_ygemm<<<dim3(33, 16), 256, 0, stream>>>(S1h, S1l, S2h, S2l, Xth, Xtl, XAh, XAl);
    k_upd<<<512, 256, 0, stream>>>(XAh, XAl, WueH, WueL, eub, Rb, Hst, XAh, XAl,
                                   (t == Tc - 1) ? 2 : 1);
  }

  // decoder supports
  k_de<<<(Nn * Bc * Ec + 255) / 256, 256, 0, stream>>>(Hst, fce, DE);
  k_gram<<<dim3(16, 16), 256, 0, stream>>>(DE, Bc * Ec, S2f);
  k_softmax<<<Nn, 256, 0, stream>>>(S2f, S1f);
  k_s2<<<dim3(16, 16), 256, 0, stream>>>(S1f, S2f);
  k_split2<<<(Nn * Nn + 255) / 256, 256, 0, stream>>>(S1f, S2f, S1h, S1l, S2h, S2l);
  k_go_init<<<gNB, 256, 0, stream>>>(x, GO);

  for (int t = 0; t < Tc; t++) {
    k_fill_dec<<<gNB, 256, 0, stream>>>(GO, ycov, XAh, XAl, t);
    k_bxt<<<dim3(16, 64), 256, 0, stream>>>(nullptr, ycov, GO, Hst, Xth, Xtl, t, 1);
    k_ygemm<<<dim3(33, 16), 256, 0, stream>>>(S1h, S1l, S2h, S2l, Xth, Xtl, XAh, XAl);
    k_gate<<<512, 256, 0, stream>>>(XAh, XAl, WgdH, WgdL, dgb, Hst, Rb, XAh, XAl, 2);
    k_bxt_state<<<dim3(16, 64), 256, 0, stream>>>(XAh, XAl, Xth, Xtl, 2);
    k_ygemm<<<dim3(33, 16), 256, 0, stream>>>(S1h, S1l, S2h, S2l, Xth, Xtl, XAh, XAl);
    k_upd<<<512, 256, 0, stream>>>(XAh, XAl, WudH, WudL, dub, Rb, Hst, XAh, XAl, 2);
    k_proj<<<gNB, 256, 0, stream>>>(Hst, pw, pb, GO, out, t);
  }
}